// Round 9
// baseline (231.751 us; speedup 1.0000x reference)
//
#include <hip/hip_runtime.h>

// Problem constants
#define BATCH 32
#define CCH 3
#define HW_TEX (512 * 512)
#define N_TEX (HW_TEX * CCH)          // 786432 per-sample flat texture (channels-last)
#define OH 128
#define OW 64
#define P_OUT (OH * OW)               // 8192
#define M_OUT (P_OUT * CCH)           // 24576 rows per sample (96 KB as f32)
#define NNZ 98304
#define OUT_ELEMS (BATCH * M_OUT)     // 786432

#define NQ 4                           // nnz quarters in phase B
#define WS_NEED ((size_t)BATCH * NNZ * 4 + (size_t)BATCH * NQ * M_OUT * 4)  // 12.6+12.6 MB

// ---------------- Phase A: pure gather, zero dependencies -------------------
// g[b,k] = vals[b,k] * x[b, cols[b,k]]. 1536 blocks x 256 thr x 8 nnz.
// No LDS, no barriers, no branches: all loads independent -> deep MLP.
// Mask copy folded in (2 floats/thread).
__global__ __launch_bounds__(256) void gather_kernel(
    const float* __restrict__ x,
    const int*   __restrict__ cols,
    const float* __restrict__ vals,
    float* __restrict__ g,
    const float* __restrict__ mask,
    float* __restrict__ out) {
    const int blk = blockIdx.x;            // 1536 = 32 samples x 48
    const int s   = blk / 48;
    const int t   = threadIdx.x;
    const size_t off = (size_t)s * NNZ + (size_t)(blk % 48) * 2048;

    const int4*   c4 = reinterpret_cast<const int4*>(cols + off);
    const float4* v4 = reinterpret_cast<const float4*>(vals + off);
    float4*       g4 = reinterpret_cast<float4*>(g + off);
    const float*  xs = x + (size_t)s * N_TEX;

    int4   ca = c4[t],       cb = c4[t + 256];
    float4 va = v4[t],       vb = v4[t + 256];

    float4 ga, gb;
    ga.x = va.x * xs[(ca.x % CCH) * HW_TEX + ca.x / CCH];
    ga.y = va.y * xs[(ca.y % CCH) * HW_TEX + ca.y / CCH];
    ga.z = va.z * xs[(ca.z % CCH) * HW_TEX + ca.z / CCH];
    ga.w = va.w * xs[(ca.w % CCH) * HW_TEX + ca.w / CCH];
    gb.x = vb.x * xs[(cb.x % CCH) * HW_TEX + cb.x / CCH];
    gb.y = vb.y * xs[(cb.y % CCH) * HW_TEX + cb.y / CCH];
    gb.z = vb.z * xs[(cb.z % CCH) * HW_TEX + cb.z / CCH];
    gb.w = vb.w * xs[(cb.w % CCH) * HW_TEX + cb.w / CCH];

    g4[t]       = ga;
    g4[t + 256] = gb;

    // mask passthrough: 1536*256 float2 = 786432 floats
    reinterpret_cast<float2*>(out + OUT_ELEMS)[blk * 256 + t] =
        reinterpret_cast<const float2*>(mask)[blk * 256 + t];
}

// ---------------- Phase B: streaming scatter into full-row LDS --------------
// 128 blocks = 32 samples x 4 quarters; 1024 thr; 96 KB LDS (full M rows).
// rows + g are COALESCED streams (no random access at all).
__global__ __launch_bounds__(1024) void scatter_kernel(
    const int*   __restrict__ rows,
    const float* __restrict__ g,
    float* __restrict__ partial) {
    __shared__ __align__(16) float acc[M_OUT];

    const int blk = blockIdx.x;
    const int s   = blk >> 2;
    const int q   = blk & 3;
    const int t   = threadIdx.x;

    float4* acc4 = reinterpret_cast<float4*>(acc);
#pragma unroll
    for (int j = 0; j < M_OUT / 4 / 1024; ++j)      // 6 per thread
        acc4[t + j * 1024] = make_float4(0.f, 0.f, 0.f, 0.f);
    __syncthreads();

    const size_t off = (size_t)s * NNZ + (size_t)q * (NNZ / NQ);   // 24576 nnz
    const int4*   r4 = reinterpret_cast<const int4*>(rows + off);
    const float4* g4 = reinterpret_cast<const float4*>(g + off);

#pragma unroll
    for (int j = 0; j < 6; ++j) {                   // 24 nnz/thread
        int4   r = r4[j * 1024 + t];
        float4 v = g4[j * 1024 + t];
        atomicAdd(&acc[r.x], v.x);
        atomicAdd(&acc[r.y], v.y);
        atomicAdd(&acc[r.z], v.z);
        atomicAdd(&acc[r.w], v.w);
    }
    __syncthreads();

    float4* pp = reinterpret_cast<float4*>(partial + (size_t)blk * M_OUT);
#pragma unroll
    for (int j = 0; j < M_OUT / 4 / 1024; ++j)
        pp[t + j * 1024] = acc4[t + j * 1024];
}

// ---------------- Phase C: sum 4 partials, CHW transform --------------------
__global__ __launch_bounds__(256) void reduce_kernel(
    const float* __restrict__ partial,
    float* __restrict__ out) {
    int tid = blockIdx.x * 256 + threadIdx.x;       // over OUT_ELEMS/4
    if (tid >= OUT_ELEMS / 4) return;
    int s    = tid / (M_OUT / 4);
    int rcl4 = (tid % (M_OUT / 4)) * 4;             // 4 consecutive channels-last rows

    const float4* pp = reinterpret_cast<const float4*>(
        partial + (size_t)(s * NQ) * M_OUT + rcl4);
    float4 sum = make_float4(0.f, 0.f, 0.f, 0.f);
#pragma unroll
    for (int q = 0; q < NQ; ++q) {
        float4 p = pp[(size_t)q * (M_OUT / 4)];
        sum.x += p.x; sum.y += p.y; sum.z += p.z; sum.w += p.w;
    }
    float* ob = out + (size_t)s * M_OUT;
    ob[(rcl4 + 0) % CCH * P_OUT + (rcl4 + 0) / CCH] = sum.x;
    ob[(rcl4 + 1) % CCH * P_OUT + (rcl4 + 1) / CCH] = sum.y;
    ob[(rcl4 + 2) % CCH * P_OUT + (rcl4 + 2) / CCH] = sum.z;
    ob[(rcl4 + 3) % CCH * P_OUT + (rcl4 + 3) / CCH] = sum.w;
}

// ---------------- Fallback (R2): no workspace needed ------------------------
#define CHUNKS 8
#define RPC (M_OUT / CHUNKS)
#define BLOCK 1024
__global__ __launch_bounds__(BLOCK) void spmm_chunk_kernel(
    const float* __restrict__ x,
    const int*   __restrict__ rows,
    const int*   __restrict__ cols,
    const float* __restrict__ vals,
    const float* __restrict__ mask,
    float* __restrict__ out) {
    __shared__ float acc[RPC];
    const int blk = blockIdx.x;
    const int s   = blk / CHUNKS;
    const int c   = blk % CHUNKS;
    const int t   = threadIdx.x;
    const int rbase = c * RPC;
#pragma unroll
    for (int j = 0; j < RPC / BLOCK; ++j) acc[t + j * BLOCK] = 0.0f;
    __syncthreads();
    const int*   rs = rows + (size_t)s * NNZ;
    const int*   cs = cols + (size_t)s * NNZ;
    const float* vs = vals + (size_t)s * NNZ;
    const float* xs = x    + (size_t)s * N_TEX;
#pragma unroll 4
    for (int i = t; i < NNZ; i += BLOCK) {
        int r = rs[i];
        unsigned lr = (unsigned)(r - rbase);
        if (lr < (unsigned)RPC) {
            int   col = cs[i];
            float v   = vs[i];
            atomicAdd(&acc[lr], v * xs[(col % CCH) * HW_TEX + col / CCH]);
        }
    }
    __syncthreads();
    const size_t outbase = (size_t)s * M_OUT;
#pragma unroll
    for (int ch = 0; ch < CCH; ++ch)
        out[outbase + (size_t)ch * P_OUT + c * (P_OUT / CHUNKS) + t] = acc[t * CCH + ch];
    {
        float* mout = out + OUT_ELEMS;
        const int base = blk * RPC;
#pragma unroll
        for (int j = 0; j < RPC / BLOCK; ++j)
            mout[base + j * BLOCK + t] = mask[base + j * BLOCK + t];
    }
}

extern "C" void kernel_launch(void* const* d_in, const int* in_sizes, int n_in,
                              void* d_out, int out_size, void* d_ws, size_t ws_size,
                              hipStream_t stream) {
    const float* x    = (const float*)d_in[0];
    const int*   rows = (const int*)  d_in[1];
    const int*   cols = (const int*)  d_in[2];
    const float* vals = (const float*)d_in[3];
    const float* mask = (const float*)d_in[4];
    float* out = (float*)d_out;

    if (ws_size >= WS_NEED) {
        float* g       = (float*)d_ws;
        float* partial = g + (size_t)BATCH * NNZ;
        gather_kernel<<<1536, 256, 0, stream>>>(x, cols, vals, g, mask, out);
        scatter_kernel<<<BATCH * NQ, 1024, 0, stream>>>(rows, g, partial);
        reduce_kernel<<<(OUT_ELEMS / 4 + 255) / 256, 256, 0, stream>>>(partial, out);
    } else {
        spmm_chunk_kernel<<<BATCH * CHUNKS, BLOCK, 0, stream>>>(x, rows, cols, vals, mask, out);
    }
}